// Round 1
// baseline (216.258 us; speedup 1.0000x reference)
//
#include <hip/hip_runtime.h>
#include <hip/hip_cooperative_groups.h>
#include <math.h>

// EdgeConv: B=16, N=8192, K=20, D=64
// h[b,n,k,o] = Y1[b,idx,o] + Bs[b,n,o];  out = GELU(LN(max_k h))
// Y1[p][o] = sum_d x[p][d]*W[o][d]          (bf16 table, gathered)
// Bs[p][o] = sum_d x[p][d]*(W[o][64+d]-W[o][d])   (kept in LDS in fused path)
#define B_ 16
#define N_ 8192
#define K_ 20
#define NPTS (B_ * N_)   // 131072

typedef __attribute__((ext_vector_type(4))) float f4;
typedef __attribute__((ext_vector_type(8))) short s8;          // 8 x bf16 MFMA fragment
typedef __attribute__((ext_vector_type(4))) unsigned int u4;   // 16B untyped
typedef __attribute__((ext_vector_type(4))) unsigned short us4;// 8B packed bf16
typedef __attribute__((ext_vector_type(4))) int i4;            // 16B index load

__device__ __forceinline__ unsigned short f2bf(float f) {
    union { float f; unsigned u; } v; v.f = f;
    return (unsigned short)((v.u + 0x7FFFu + ((v.u >> 16) & 1u)) >> 16);   // RNE
}
__device__ __forceinline__ float bfhi(unsigned w) { return __uint_as_float(w & 0xFFFF0000u); }
__device__ __forceinline__ float bflo(unsigned w) { return __uint_as_float(w << 16); }
__device__ __forceinline__ float max3f(float a, float b, float c) {
    float d;
    asm("v_max3_f32 %0, %1, %2, %3" : "=v"(d) : "v"(a), "v"(b), "v"(c));
    return d;
}

// =====================================================================
// Fused cooperative kernel: 512 blocks x 256 threads.
// Block g owns 256 consecutive points of batch b = (g&7) + 8*((g>>3)&1)
// (keeps batch->XCD pinning for gather L2 locality; perf-only).
// Phase A: W fragments -> registers (no prep kernel, no Wl LDS)
// Phase B: projection: Y1 -> global (nt), Bs -> LDS (never HBM)
// grid.sync()  (agent-scope release/acquire: L2 wb+inv -> Y1 visible)
// Phase C: gather + max3 + LN + GELU
// =====================================================================
__global__ __launch_bounds__(256, 3) void fused_kernel(
    const float* __restrict__ x, const int* __restrict__ ind,
    const float* __restrict__ W, const float* __restrict__ gamma,
    const float* __restrict__ beta, float* __restrict__ out,
    unsigned short* __restrict__ Y1)
{
    __shared__ unsigned short BsL[256 * 72];   // row stride 144 B (16B-aligned reads)

    const int t = threadIdx.x;
    const int lane = t & 63, wv = t >> 6;
    const int g = blockIdx.x;                  // 512 blocks
    const int b = (g & 7) + 8 * ((g >> 3) & 1);
    const int z = g >> 4;                      // 0..31
    const int p0 = b * N_ + z * 256;

    // ---------- Phase A: combined-W fragments in registers ----------
    const int mm = lane & 15, qq = lane >> 4;
    s8 wf[16];   // wf[tt*2+s]: A[row=16tt+mm][k = s*32 + qq*8 + j]
#pragma unroll
    for (int tt = 0; tt < 8; ++tt) {
#pragma unroll
        for (int s = 0; s < 2; ++s) {
            const int k0 = s * 32 + qq * 8;
            s8 w;
            if (tt < 4) {
                const int row = 16 * tt + mm;
                f4 a0 = *(const f4*)&W[row * 128 + k0];
                f4 a1 = *(const f4*)&W[row * 128 + k0 + 4];
                w[0]=(short)f2bf(a0.x); w[1]=(short)f2bf(a0.y);
                w[2]=(short)f2bf(a0.z); w[3]=(short)f2bf(a0.w);
                w[4]=(short)f2bf(a1.x); w[5]=(short)f2bf(a1.y);
                w[6]=(short)f2bf(a1.z); w[7]=(short)f2bf(a1.w);
            } else {
                const int row = 16 * (tt - 4) + mm;
                f4 a0 = *(const f4*)&W[row * 128 + 64 + k0];
                f4 a1 = *(const f4*)&W[row * 128 + 64 + k0 + 4];
                f4 c0 = *(const f4*)&W[row * 128 + k0];
                f4 c1 = *(const f4*)&W[row * 128 + k0 + 4];
                w[0]=(short)f2bf(a0.x-c0.x); w[1]=(short)f2bf(a0.y-c0.y);
                w[2]=(short)f2bf(a0.z-c0.z); w[3]=(short)f2bf(a0.w-c0.w);
                w[4]=(short)f2bf(a1.x-c1.x); w[5]=(short)f2bf(a1.y-c1.y);
                w[6]=(short)f2bf(a1.z-c1.z); w[7]=(short)f2bf(a1.w-c1.w);
            }
            wf[tt * 2 + s] = w;
        }
    }

    // ---------- Phase B: projection, 4 tiles of 64 points ----------
#pragma unroll 2
    for (int tile = 0; tile < 4; ++tile) {
        const int plocal = tile * 64 + wv * 16 + mm;     // 0..255
        const int pg = p0 + plocal;
        const float* xr = x + (size_t)pg * 64 + qq * 8;
        f4 x0 = __builtin_nontemporal_load((const f4*)xr);
        f4 x1 = __builtin_nontemporal_load((const f4*)(xr + 4));
        f4 x2 = __builtin_nontemporal_load((const f4*)(xr + 32));
        f4 x3 = __builtin_nontemporal_load((const f4*)(xr + 36));
        s8 X0, X1;
        X0[0]=(short)f2bf(x0.x); X0[1]=(short)f2bf(x0.y); X0[2]=(short)f2bf(x0.z); X0[3]=(short)f2bf(x0.w);
        X0[4]=(short)f2bf(x1.x); X0[5]=(short)f2bf(x1.y); X0[6]=(short)f2bf(x1.z); X0[7]=(short)f2bf(x1.w);
        X1[0]=(short)f2bf(x2.x); X1[1]=(short)f2bf(x2.y); X1[2]=(short)f2bf(x2.z); X1[3]=(short)f2bf(x2.w);
        X1[4]=(short)f2bf(x3.x); X1[5]=(short)f2bf(x3.y); X1[6]=(short)f2bf(x3.z); X1[7]=(short)f2bf(x3.w);

        f4 acc[8];
#pragma unroll
        for (int tt = 0; tt < 8; ++tt) acc[tt] = (f4)0.f;
#pragma unroll
        for (int s = 0; s < 2; ++s) {
            const s8 X = s ? X1 : X0;
#pragma unroll
            for (int tt = 0; tt < 8; ++tt)
                acc[tt] = __builtin_amdgcn_mfma_f32_16x16x32_bf16(wf[tt * 2 + s], X, acc[tt], 0, 0, 0);
        }

        const size_t prow = (size_t)pg * 64;
#pragma unroll
        for (int tt = 0; tt < 4; ++tt) {
            us4 u;
            u.x = f2bf(acc[tt][0]); u.y = f2bf(acc[tt][1]);
            u.z = f2bf(acc[tt][2]); u.w = f2bf(acc[tt][3]);
            __builtin_nontemporal_store(u, (us4*)&Y1[prow + tt * 16 + qq * 4]);
        }
#pragma unroll
        for (int tt = 4; tt < 8; ++tt) {
            us4 u;
            u.x = f2bf(acc[tt][0]); u.y = f2bf(acc[tt][1]);
            u.z = f2bf(acc[tt][2]); u.w = f2bf(acc[tt][3]);
            *(us4*)((char*)BsL + plocal * 144 + (tt - 4) * 32 + qq * 8) = u;
        }
    }

    cooperative_groups::this_grid().sync();

    // ---------- Phase C: gather + max + LN + GELU ----------
    const int sub = lane & 7;            // channel group (8 ch)
    const int qp = lane >> 3;            // point within wave
    const f4 g0 = *(const f4*)&gamma[sub * 8];
    const f4 g1 = *(const f4*)&gamma[sub * 8 + 4];
    const f4 be0 = *(const f4*)&beta[sub * 8];
    const f4 be1 = *(const f4*)&beta[sub * 8 + 4];
    const unsigned short* tbl = Y1 + (size_t)b * (N_ * 64) + sub * 8;

#pragma unroll 1
    for (int pass = 0; pass < 8; ++pass) {
        const int pl = pass * 32 + wv * 8 + qp;          // 0..255
        const int pg = p0 + pl;

        int idxs[K_];
        const i4* ip = (const i4*)&ind[pg * K_];         // 80B/point, 16B-aligned
#pragma unroll
        for (int v = 0; v < 5; ++v) {
            i4 iv = __builtin_nontemporal_load(ip + v);
            idxs[4 * v + 0] = iv.x; idxs[4 * v + 1] = iv.y;
            idxs[4 * v + 2] = iv.z; idxs[4 * v + 3] = iv.w;
        }

        f4 ma = (f4)(-INFINITY), mb = (f4)(-INFINITY);
#pragma unroll
        for (int r = 0; r < 2; ++r) {        // 2 rounds x 10 outstanding 16B gathers
            u4 rv[10];
#pragma unroll
            for (int k = 0; k < 10; ++k)
                rv[k] = *(const u4*)(tbl + idxs[r * 10 + k] * 64);
#pragma unroll
            for (int k = 0; k < 10; k += 2) {
                u4 a = rv[k], c = rv[k + 1];
                ma.x = max3f(ma.x, bflo(a.x), bflo(c.x));
                ma.y = max3f(ma.y, bfhi(a.x), bfhi(c.x));
                ma.z = max3f(ma.z, bflo(a.y), bflo(c.y));
                ma.w = max3f(ma.w, bfhi(a.y), bfhi(c.y));
                mb.x = max3f(mb.x, bflo(a.z), bflo(c.z));
                mb.y = max3f(mb.y, bfhi(a.z), bfhi(c.z));
                mb.z = max3f(mb.z, bflo(a.w), bflo(c.w));
                mb.w = max3f(mb.w, bfhi(a.w), bfhi(c.w));
            }
        }

        const u4 bsv = *(const u4*)((const char*)BsL + pl * 144 + sub * 16);
        f4 ha, hb;
        ha.x = ma.x + bflo(bsv.x); ha.y = ma.y + bfhi(bsv.x);
        ha.z = ma.z + bflo(bsv.y); ha.w = ma.w + bfhi(bsv.y);
        hb.x = mb.x + bflo(bsv.z); hb.y = mb.y + bfhi(bsv.z);
        hb.z = mb.z + bflo(bsv.w); hb.w = mb.w + bfhi(bsv.w);

        // LayerNorm over 64 ch = 8 comps x 8 lanes (xor masks 1,2,4 stay in-group)
        float s = ha.x + ha.y + ha.z + ha.w + hb.x + hb.y + hb.z + hb.w;
#pragma unroll
        for (int off = 4; off >= 1; off >>= 1) s += __shfl_xor(s, off, 64);
        const float mu = s * (1.0f / 64.0f);
        f4 da = ha - mu, db = hb - mu;
        float v2 = da.x * da.x + da.y * da.y + da.z * da.z + da.w * da.w
                 + db.x * db.x + db.y * db.y + db.z * db.z + db.w * db.w;
#pragma unroll
        for (int off = 4; off >= 1; off >>= 1) v2 += __shfl_xor(v2, off, 64);
        const float rstd = rsqrtf(v2 * (1.0f / 64.0f) + 1e-5f);

        f4 na = da * rstd * g0 + be0;
        f4 nb = db * rstd * g1 + be1;

        f4 r0, r1;
        r0.x = 0.5f * na.x * (1.0f + erff(na.x * 0.70710678f));
        r0.y = 0.5f * na.y * (1.0f + erff(na.y * 0.70710678f));
        r0.z = 0.5f * na.z * (1.0f + erff(na.z * 0.70710678f));
        r0.w = 0.5f * na.w * (1.0f + erff(na.w * 0.70710678f));
        r1.x = 0.5f * nb.x * (1.0f + erff(nb.x * 0.70710678f));
        r1.y = 0.5f * nb.y * (1.0f + erff(nb.y * 0.70710678f));
        r1.z = 0.5f * nb.z * (1.0f + erff(nb.z * 0.70710678f));
        r1.w = 0.5f * nb.w * (1.0f + erff(nb.w * 0.70710678f));
        float* op = &out[(size_t)pg * 64 + sub * 8];
        __builtin_nontemporal_store(r0, (f4*)op);
        __builtin_nontemporal_store(r1, (f4*)(op + 4));
    }
}

// =====================================================================
// Fallback path (exact previous proven kernels) — used only if the
// cooperative launch is rejected (capture-unsupported / co-residency).
// =====================================================================
__global__ __launch_bounds__(256) void prep_kernel(const float* __restrict__ W,
                                                   unsigned short* __restrict__ Wg) {
    const int i = blockIdx.x * 256 + threadIdx.x;   // 8192 elems
    const int j = i >> 6, d = i & 63;
    const float v = (j < 64) ? W[j * 128 + d]
                             : (W[(j - 64) * 128 + 64 + d] - W[(j - 64) * 128 + d]);
    Wg[i] = f2bf(v);
}

__global__ __launch_bounds__(256) void proj_kernel(const float* __restrict__ x,
                                                   const unsigned short* __restrict__ Wg,
                                                   unsigned short* __restrict__ Y1,
                                                   unsigned short* __restrict__ Bs) {
    __shared__ unsigned short Wl[128 * 72];   // row stride 144B: 2-way bank alias = free
    const int t = threadIdx.x;

    for (int i = t; i < 1024; i += 256) {     // stage 16KB Wg, coalesced dwordx4
        u4 v = ((const u4*)Wg)[i];
        *((u4*)((char*)Wl + (i >> 3) * 144 + (i & 7) * 16)) = v;
    }
    __syncthreads();

    const int lane = t & 63;
    const int wv = t >> 6;
    const int m = lane & 15;
    const int q = lane >> 4;
    const int pbase = blockIdx.x * 64 + wv * 16;

    const float* xr = x + (size_t)(pbase + m) * 64 + q * 8;
    f4 x0 = *(const f4*)(xr);
    f4 x1 = *(const f4*)(xr + 4);
    f4 x2 = *(const f4*)(xr + 32);
    f4 x3 = *(const f4*)(xr + 36);
    s8 X0, X1;
    X0[0]=(short)f2bf(x0.x); X0[1]=(short)f2bf(x0.y); X0[2]=(short)f2bf(x0.z); X0[3]=(short)f2bf(x0.w);
    X0[4]=(short)f2bf(x1.x); X0[5]=(short)f2bf(x1.y); X0[6]=(short)f2bf(x1.z); X0[7]=(short)f2bf(x1.w);
    X1[0]=(short)f2bf(x2.x); X1[1]=(short)f2bf(x2.y); X1[2]=(short)f2bf(x2.z); X1[3]=(short)f2bf(x2.w);
    X1[4]=(short)f2bf(x3.x); X1[5]=(short)f2bf(x3.y); X1[6]=(short)f2bf(x3.z); X1[7]=(short)f2bf(x3.w);

    f4 acc[8];
#pragma unroll
    for (int tt = 0; tt < 8; ++tt) acc[tt] = (f4)0.f;

#pragma unroll
    for (int s = 0; s < 2; ++s) {
        const s8 X = s ? X1 : X0;
#pragma unroll
        for (int tt = 0; tt < 8; ++tt) {
            s8 w = *(const s8*)((const char*)Wl + (16 * tt + m) * 144 + s * 64 + q * 16);
            acc[tt] = __builtin_amdgcn_mfma_f32_16x16x32_bf16(w, X, acc[tt], 0, 0, 0);
        }
    }

    const size_t prow = (size_t)(pbase + m) * 64;
#pragma unroll
    for (int tt = 0; tt < 4; ++tt) {
        us4 u;
        u.x = f2bf(acc[tt][0]); u.y = f2bf(acc[tt][1]);
        u.z = f2bf(acc[tt][2]); u.w = f2bf(acc[tt][3]);
        *(us4*)&Y1[prow + tt * 16 + q * 4] = u;
    }
#pragma unroll
    for (int tt = 4; tt < 8; ++tt) {
        us4 u;
        u.x = f2bf(acc[tt][0]); u.y = f2bf(acc[tt][1]);
        u.z = f2bf(acc[tt][2]); u.w = f2bf(acc[tt][3]);
        *(us4*)&Bs[prow + (tt - 4) * 16 + q * 4] = u;
    }
}

__global__ __launch_bounds__(256) void gather_kernel(const unsigned short* __restrict__ Y1,
                                                     const unsigned short* __restrict__ Bs,
                                                     const int* __restrict__ ind,
                                                     const float* __restrict__ gamma,
                                                     const float* __restrict__ beta,
                                                     float* __restrict__ out) {
    const int lane = threadIdx.x & 63;
    const int wave = threadIdx.x >> 6;
    const int sub = lane & 7;
    const int q = lane >> 3;
    const int bi = blockIdx.x;
    const int bt = bi & 15;
    const int jj = bi >> 4;
    const int p = bt * N_ + jj * 32 + wave * 8 + q;
    const int bbase = bt * N_ * 64;

    int idxs[K_];
    const int4* ip = (const int4*)&ind[p * K_];
#pragma unroll
    for (int v = 0; v < 5; ++v) {
        int4 iv = ip[v];
        idxs[4 * v + 0] = iv.x; idxs[4 * v + 1] = iv.y;
        idxs[4 * v + 2] = iv.z; idxs[4 * v + 3] = iv.w;
    }

    f4 ma = (f4)(-INFINITY), mb = (f4)(-INFINITY);
#pragma unroll
    for (int r = 0; r < 2; ++r) {
        u4 rv[10];
#pragma unroll
        for (int k = 0; k < 10; ++k)
            rv[k] = *(const u4*)(Y1 + bbase + idxs[r * 10 + k] * 64 + sub * 8);
#pragma unroll
        for (int k = 0; k < 10; ++k) {
            ma.x = fmaxf(ma.x, bflo(rv[k].x)); ma.y = fmaxf(ma.y, bfhi(rv[k].x));
            ma.z = fmaxf(ma.z, bflo(rv[k].y)); ma.w = fmaxf(ma.w, bfhi(rv[k].y));
            mb.x = fmaxf(mb.x, bflo(rv[k].z)); mb.y = fmaxf(mb.y, bfhi(rv[k].z));
            mb.z = fmaxf(mb.z, bflo(rv[k].w)); mb.w = fmaxf(mb.w, bfhi(rv[k].w));
        }
    }

    u4 bsv = __builtin_nontemporal_load((const u4*)(Bs + (size_t)p * 64 + sub * 8));
    f4 ha, hb;
    ha.x = ma.x + bflo(bsv.x); ha.y = ma.y + bfhi(bsv.x);
    ha.z = ma.z + bflo(bsv.y); ha.w = ma.w + bfhi(bsv.y);
    hb.x = mb.x + bflo(bsv.z); hb.y = mb.y + bfhi(bsv.z);
    hb.z = mb.z + bflo(bsv.w); hb.w = mb.w + bfhi(bsv.w);

    float s = ha.x + ha.y + ha.z + ha.w + hb.x + hb.y + hb.z + hb.w;
#pragma unroll
    for (int off = 4; off >= 1; off >>= 1) s += __shfl_xor(s, off, 64);
    const float mu = s * (1.0f / 64.0f);
    f4 da = ha - mu, db = hb - mu;
    float v2 = da.x * da.x + da.y * da.y + da.z * da.z + da.w * da.w
             + db.x * db.x + db.y * db.y + db.z * db.z + db.w * db.w;
#pragma unroll
    for (int off = 4; off >= 1; off >>= 1) v2 += __shfl_xor(v2, off, 64);
    const float rstd = rsqrtf(v2 * (1.0f / 64.0f) + 1e-5f);

    const f4 g0 = *(const f4*)&gamma[sub * 8];
    const f4 g1 = *(const f4*)&gamma[sub * 8 + 4];
    const f4 b0 = *(const f4*)&beta[sub * 8];
    const f4 b1 = *(const f4*)&beta[sub * 8 + 4];
    f4 na = da * rstd * g0 + b0;
    f4 nb = db * rstd * g1 + b1;

    f4 r0, r1;
    r0.x = 0.5f * na.x * (1.0f + erff(na.x * 0.70710678f));
    r0.y = 0.5f * na.y * (1.0f + erff(na.y * 0.70710678f));
    r0.z = 0.5f * na.z * (1.0f + erff(na.z * 0.70710678f));
    r0.w = 0.5f * na.w * (1.0f + erff(na.w * 0.70710678f));
    r1.x = 0.5f * nb.x * (1.0f + erff(nb.x * 0.70710678f));
    r1.y = 0.5f * nb.y * (1.0f + erff(nb.y * 0.70710678f));
    r1.z = 0.5f * nb.z * (1.0f + erff(nb.z * 0.70710678f));
    r1.w = 0.5f * nb.w * (1.0f + erff(nb.w * 0.70710678f));
    float* op = &out[(size_t)p * 64 + sub * 8];
    __builtin_nontemporal_store(r0, (f4*)op);
    __builtin_nontemporal_store(r1, (f4*)(op + 4));
}

extern "C" void kernel_launch(void* const* d_in, const int* in_sizes, int n_in,
                              void* d_out, int out_size, void* d_ws, size_t ws_size,
                              hipStream_t stream) {
    const float* x     = (const float*)d_in[0];
    const int*   ind   = (const int*)d_in[1];
    const float* W     = (const float*)d_in[2];
    const float* gamma = (const float*)d_in[3];
    const float* beta  = (const float*)d_in[4];
    float* out = (float*)d_out;

    unsigned short* Bs = (unsigned short*)d_ws;          // 16.8 MB bf16 (fallback only)
    unsigned short* Y1 = Bs + (size_t)NPTS * 64;         // 16.8 MB bf16
    unsigned short* Wg = Y1 + (size_t)NPTS * 64;         // 16 KB bf16 (fallback only)

    void* args[] = {(void*)&x, (void*)&ind, (void*)&W, (void*)&gamma,
                    (void*)&beta, (void*)&out, (void*)&Y1};
    hipError_t e = hipLaunchCooperativeKernel((const void*)fused_kernel,
                                              dim3(512), dim3(256), args, 0, stream);
    if (e != hipSuccess) {
        // Fallback: proven 3-kernel pipeline
        prep_kernel<<<32, 256, 0, stream>>>(W, Wg);
        proj_kernel<<<NPTS / 64, 256, 0, stream>>>(x, Wg, Y1, Bs);
        gather_kernel<<<NPTS / 32, 256, 0, stream>>>(Y1, Bs, ind, gamma, beta, out);
    }
}

// Round 2
// 137.772 us; speedup vs baseline: 1.5697x; 1.5697x over previous
//
#include <hip/hip_runtime.h>
#include <math.h>

// EdgeConv: B=16, N=8192, K=20, D=64
// h[b,n,k,o] = Y1[b,idx,o] + Bs[b,n,o];  out = GELU(LN(max_k h))
// Y1[p][o] = sum_d x[p][d]*W[o][d]          (bf16 table, gathered)
// Bs[p][o] = sum_d x[p][d]*(W[o][64+d]-W[o][d])   (bf16, streamed)
// 2-kernel pipeline (prep folded into proj). High-TLP gather: 4096 blocks.
#define B_ 16
#define N_ 8192
#define K_ 20
#define NPTS (B_ * N_)   // 131072

typedef __attribute__((ext_vector_type(4))) float f4;
typedef __attribute__((ext_vector_type(8))) short s8;          // 8 x bf16 MFMA fragment
typedef __attribute__((ext_vector_type(4))) unsigned int u4;   // 16B untyped
typedef __attribute__((ext_vector_type(4))) unsigned short us4;// 8B packed bf16
typedef __attribute__((ext_vector_type(4))) int i4;            // 16B index load

__device__ __forceinline__ unsigned short f2bf(float f) {
    union { float f; unsigned u; } v; v.f = f;
    return (unsigned short)((v.u + 0x7FFFu + ((v.u >> 16) & 1u)) >> 16);   // RNE
}
__device__ __forceinline__ float bfhi(unsigned w) { return __uint_as_float(w & 0xFFFF0000u); }
__device__ __forceinline__ float bflo(unsigned w) { return __uint_as_float(w << 16); }
__device__ __forceinline__ float max3f(float a, float b, float c) {
    float d;
    asm("v_max3_f32 %0, %1, %2, %3" : "=v"(d) : "v"(a), "v"(b), "v"(c));
    return d;
}

// ---------------- Kernel 1: projections via MFMA (A=W, B=x) ----------------
// W staging folded in: combined Wg (rows 0..63 = W[:, d]; rows 64..127 =
// W[:, 64+d]-W[:, d]) built from L2-resident W directly into LDS.
// Each wave: 16 points x 128 outputs. D-layout: row(o-in-tile)=q*4+j, col(point)=m.
// => lane's 4 acc regs are 4 CONSECUTIVE output channels -> packed 8B stores.
__global__ __launch_bounds__(256) void proj_kernel(const float* __restrict__ x,
                                                   const float* __restrict__ W,
                                                   unsigned short* __restrict__ Y1,
                                                   unsigned short* __restrict__ Bs) {
    __shared__ unsigned short Wl[128 * 72];   // row stride 144B: 2-way bank alias = free
    const int t = threadIdx.x;

    // Stage combined W: 8192 bf16 elems as 2048 x 4-elem chunks, 8 iters/thread.
    // W is 32KB -> L1/L2-hot after first block; coalesced f4 reads.
    for (int i = t; i < 2048; i += 256) {
        const int j = i >> 4, d0 = (i & 15) * 4;
        f4 v;
        if (j < 64) {
            v = *(const f4*)&W[j * 128 + d0];
        } else {
            f4 a = *(const f4*)&W[(j - 64) * 128 + 64 + d0];
            f4 c = *(const f4*)&W[(j - 64) * 128 + d0];
            v = a - c;
        }
        us4 u;
        u.x = f2bf(v.x); u.y = f2bf(v.y); u.z = f2bf(v.z); u.w = f2bf(v.w);
        *(us4*)((char*)Wl + j * 144 + d0 * 2) = u;
    }
    __syncthreads();

    const int lane = t & 63;
    const int wv = t >> 6;
    const int m = lane & 15;          // point-within-tile (B idx) AND W-row-within-tile (A idx)
    const int q = lane >> 4;
    const int pbase = blockIdx.x * 64 + wv * 16;

    // B-frag (x): lane reads 16B-contig chunks of its point's row (streamed: nt)
    const float* xr = x + (size_t)(pbase + m) * 64 + q * 8;
    f4 x0 = __builtin_nontemporal_load((const f4*)(xr));
    f4 x1 = __builtin_nontemporal_load((const f4*)(xr + 4));
    f4 x2 = __builtin_nontemporal_load((const f4*)(xr + 32));
    f4 x3 = __builtin_nontemporal_load((const f4*)(xr + 36));
    s8 X0, X1;
    X0[0]=(short)f2bf(x0.x); X0[1]=(short)f2bf(x0.y); X0[2]=(short)f2bf(x0.z); X0[3]=(short)f2bf(x0.w);
    X0[4]=(short)f2bf(x1.x); X0[5]=(short)f2bf(x1.y); X0[6]=(short)f2bf(x1.z); X0[7]=(short)f2bf(x1.w);
    X1[0]=(short)f2bf(x2.x); X1[1]=(short)f2bf(x2.y); X1[2]=(short)f2bf(x2.z); X1[3]=(short)f2bf(x2.w);
    X1[4]=(short)f2bf(x3.x); X1[5]=(short)f2bf(x3.y); X1[6]=(short)f2bf(x3.z); X1[7]=(short)f2bf(x3.w);

    f4 acc[8];
#pragma unroll
    for (int tt = 0; tt < 8; ++tt) acc[tt] = (f4)0.f;

#pragma unroll
    for (int s = 0; s < 2; ++s) {
        const s8 X = s ? X1 : X0;
#pragma unroll
        for (int tt = 0; tt < 8; ++tt) {
            // A-frag (W): A[m][k=s*32+q*8+j], 16B-aligned in padded LDS
            s8 w = *(const s8*)((const char*)Wl + (16 * tt + m) * 144 + s * 64 + q * 16);
            acc[tt] = __builtin_amdgcn_mfma_f32_16x16x32_bf16(w, X, acc[tt], 0, 0, 0);
        }
    }

    // D: o = 16*tt + q*4 + j, point = pbase + m  -> packed us4 (8B) stores
    const size_t prow = (size_t)(pbase + m) * 64;
#pragma unroll
    for (int tt = 0; tt < 4; ++tt) {
        us4 u;
        u.x = f2bf(acc[tt][0]); u.y = f2bf(acc[tt][1]);
        u.z = f2bf(acc[tt][2]); u.w = f2bf(acc[tt][3]);
        *(us4*)&Y1[prow + tt * 16 + q * 4] = u;
    }
#pragma unroll
    for (int tt = 4; tt < 8; ++tt) {
        us4 u;
        u.x = f2bf(acc[tt][0]); u.y = f2bf(acc[tt][1]);
        u.z = f2bf(acc[tt][2]); u.w = f2bf(acc[tt][3]);
        *(us4*)&Bs[prow + (tt - 4) * 16 + q * 4] = u;
    }
}

// ---------------- Kernel 2: gather + max + LN + GELU ----------------
// 8 points/wave, 8 lanes/point, 8 ch/lane: 16B gathers (half the VMEM instrs).
// XCD-pinned: batch bt = blockIdx&15 -> XCD bt%8 caches 2 batches (2.1MB bf16 table).
// v_max3_f32 halves the max-chain VALU count vs pairwise fmaxf.
__global__ __launch_bounds__(256) void gather_kernel(const unsigned short* __restrict__ Y1,
                                                     const unsigned short* __restrict__ Bs,
                                                     const int* __restrict__ ind,
                                                     const float* __restrict__ gamma,
                                                     const float* __restrict__ beta,
                                                     float* __restrict__ out) {
    const int lane = threadIdx.x & 63;
    const int wave = threadIdx.x >> 6;
    const int sub = lane & 7;            // channel group (8 ch)
    const int q = lane >> 3;             // point within wave
    const int bi = blockIdx.x;           // 4096 blocks
    const int bt = bi & 15;
    const int jj = bi >> 4;
    const int p = bt * N_ + jj * 32 + wave * 8 + q;
    const int bbase = bt * N_ * 64;

    int idxs[K_];
    const i4* ip = (const i4*)&ind[p * K_];   // 80B/point, 16B-aligned (nt: streamed once)
#pragma unroll
    for (int v = 0; v < 5; ++v) {
        i4 iv = __builtin_nontemporal_load(ip + v);
        idxs[4 * v + 0] = iv.x; idxs[4 * v + 1] = iv.y;
        idxs[4 * v + 2] = iv.z; idxs[4 * v + 3] = iv.w;
    }

    f4 ma = (f4)(-INFINITY), mb = (f4)(-INFINITY);
#pragma unroll
    for (int r = 0; r < 2; ++r) {        // 2 rounds x 10 outstanding 16B gathers
        u4 rv[10];
#pragma unroll
        for (int k = 0; k < 10; ++k)
            rv[k] = *(const u4*)(Y1 + bbase + idxs[r * 10 + k] * 64 + sub * 8);
#pragma unroll
        for (int k = 0; k < 10; k += 2) {
            u4 a = rv[k], c = rv[k + 1];
            ma.x = max3f(ma.x, bflo(a.x), bflo(c.x));
            ma.y = max3f(ma.y, bfhi(a.x), bfhi(c.x));
            ma.z = max3f(ma.z, bflo(a.y), bflo(c.y));
            ma.w = max3f(ma.w, bfhi(a.y), bfhi(c.y));
            mb.x = max3f(mb.x, bflo(a.z), bflo(c.z));
            mb.y = max3f(mb.y, bfhi(a.z), bfhi(c.z));
            mb.z = max3f(mb.z, bflo(a.w), bflo(c.w));
            mb.w = max3f(mb.w, bfhi(a.w), bfhi(c.w));
        }
    }

    u4 bsv = __builtin_nontemporal_load((const u4*)(Bs + (size_t)p * 64 + sub * 8));
    f4 ha, hb;
    ha.x = ma.x + bflo(bsv.x); ha.y = ma.y + bfhi(bsv.x);
    ha.z = ma.z + bflo(bsv.y); ha.w = ma.w + bfhi(bsv.y);
    hb.x = mb.x + bflo(bsv.z); hb.y = mb.y + bfhi(bsv.z);
    hb.z = mb.z + bflo(bsv.w); hb.w = mb.w + bfhi(bsv.w);

    // LayerNorm over 64 ch = 8 comps x 8 lanes (xor masks 1,2,4 stay in-group)
    float s = ha.x + ha.y + ha.z + ha.w + hb.x + hb.y + hb.z + hb.w;
#pragma unroll
    for (int off = 4; off >= 1; off >>= 1) s += __shfl_xor(s, off, 64);
    const float mu = s * (1.0f / 64.0f);
    f4 da = ha - mu, db = hb - mu;
    float v2 = da.x * da.x + da.y * da.y + da.z * da.z + da.w * da.w
             + db.x * db.x + db.y * db.y + db.z * db.z + db.w * db.w;
#pragma unroll
    for (int off = 4; off >= 1; off >>= 1) v2 += __shfl_xor(v2, off, 64);
    const float rstd = rsqrtf(v2 * (1.0f / 64.0f) + 1e-5f);

    const f4 g0 = *(const f4*)&gamma[sub * 8];
    const f4 g1 = *(const f4*)&gamma[sub * 8 + 4];
    const f4 b0 = *(const f4*)&beta[sub * 8];
    const f4 b1 = *(const f4*)&beta[sub * 8 + 4];
    f4 na = da * rstd * g0 + b0;
    f4 nb = db * rstd * g1 + b1;

    f4 r0, r1;
    r0.x = 0.5f * na.x * (1.0f + erff(na.x * 0.70710678f));
    r0.y = 0.5f * na.y * (1.0f + erff(na.y * 0.70710678f));
    r0.z = 0.5f * na.z * (1.0f + erff(na.z * 0.70710678f));
    r0.w = 0.5f * na.w * (1.0f + erff(na.w * 0.70710678f));
    r1.x = 0.5f * nb.x * (1.0f + erff(nb.x * 0.70710678f));
    r1.y = 0.5f * nb.y * (1.0f + erff(nb.y * 0.70710678f));
    r1.z = 0.5f * nb.z * (1.0f + erff(nb.z * 0.70710678f));
    r1.w = 0.5f * nb.w * (1.0f + erff(nb.w * 0.70710678f));
    float* op = &out[(size_t)p * 64 + sub * 8];
    __builtin_nontemporal_store(r0, (f4*)op);
    __builtin_nontemporal_store(r1, (f4*)(op + 4));
}

extern "C" void kernel_launch(void* const* d_in, const int* in_sizes, int n_in,
                              void* d_out, int out_size, void* d_ws, size_t ws_size,
                              hipStream_t stream) {
    const float* x     = (const float*)d_in[0];
    const int*   ind   = (const int*)d_in[1];
    const float* W     = (const float*)d_in[2];
    const float* gamma = (const float*)d_in[3];
    const float* beta  = (const float*)d_in[4];
    float* out = (float*)d_out;

    unsigned short* Bs = (unsigned short*)d_ws;          // 16.8 MB bf16
    unsigned short* Y1 = Bs + (size_t)NPTS * 64;         // 16.8 MB bf16

    proj_kernel<<<NPTS / 64, 256, 0, stream>>>(x, W, Y1, Bs);
    gather_kernel<<<NPTS / 32, 256, 0, stream>>>(Y1, Bs, ind, gamma, beta, out);
}

// Round 3
// 128.049 us; speedup vs baseline: 1.6889x; 1.0759x over previous
//
#include <hip/hip_runtime.h>
#include <math.h>

// EdgeConv: B=16, N=8192, K=20, D=64
// h[b,n,k,o] = Y1[b,idx,o] + Bs[b,n,o];  out = GELU(LN(max_k h))
// Y1[p][o] = sum_d x[p][d]*W[o][d]          (bf16 table, gathered)
// Bs[p][o] = sum_d x[p][d]*(W[o][64+d]-W[o][d])   (bf16, streamed)
#define B_ 16
#define N_ 8192
#define K_ 20
#define NPTS (B_ * N_)   // 131072

typedef __attribute__((ext_vector_type(4))) float f4;
typedef __attribute__((ext_vector_type(8))) short s8;          // 8 x bf16 MFMA fragment
typedef __attribute__((ext_vector_type(4))) unsigned int u4;   // 16B untyped
typedef __attribute__((ext_vector_type(4))) unsigned short us4;// 8B packed bf16

__device__ __forceinline__ unsigned short f2bf(float f) {
    union { float f; unsigned u; } v; v.f = f;
    return (unsigned short)((v.u + 0x7FFFu + ((v.u >> 16) & 1u)) >> 16);   // RNE
}
__device__ __forceinline__ float bfhi(unsigned w) { return __uint_as_float(w & 0xFFFF0000u); }
__device__ __forceinline__ float bflo(unsigned w) { return __uint_as_float(w << 16); }

// ---------------- Kernel 0: combined W in bf16 ----------------
// Wg[j][d], j<64 -> W[j][d] ; j>=64 -> W[j-64][64+d]-W[j-64][d]
__global__ __launch_bounds__(256) void prep_kernel(const float* __restrict__ W,
                                                   unsigned short* __restrict__ Wg) {
    const int i = blockIdx.x * 256 + threadIdx.x;   // 8192 elems
    const int j = i >> 6, d = i & 63;
    const float v = (j < 64) ? W[j * 128 + d]
                             : (W[(j - 64) * 128 + 64 + d] - W[(j - 64) * 128 + d]);
    Wg[i] = f2bf(v);
}

// ---------------- Kernel 1: projections via MFMA (A=W, B=x) ----------------
// Each wave: 16 points x 128 outputs. D-layout: row(o-in-tile)=q*4+j, col(point)=m.
// => lane's 4 acc regs are 4 CONSECUTIVE output channels -> packed 8B stores.
__global__ __launch_bounds__(256) void proj_kernel(const float* __restrict__ x,
                                                   const unsigned short* __restrict__ Wg,
                                                   unsigned short* __restrict__ Y1,
                                                   unsigned short* __restrict__ Bs) {
    __shared__ unsigned short Wl[128 * 72];   // row stride 144B: 2-way bank alias = free
    const int t = threadIdx.x;

    for (int i = t; i < 1024; i += 256) {     // stage 16KB Wg, coalesced dwordx4
        u4 v = ((const u4*)Wg)[i];
        *((u4*)((char*)Wl + (i >> 3) * 144 + (i & 7) * 16)) = v;
    }
    __syncthreads();

    const int lane = t & 63;
    const int wv = t >> 6;
    const int m = lane & 15;          // point-within-tile (B idx) AND W-row-within-tile (A idx)
    const int q = lane >> 4;
    const int pbase = blockIdx.x * 64 + wv * 16;

    // B-frag (x): lane reads 16B-contig chunks of its point's row
    const float* xr = x + (size_t)(pbase + m) * 64 + q * 8;
    f4 x0 = *(const f4*)(xr);
    f4 x1 = *(const f4*)(xr + 4);
    f4 x2 = *(const f4*)(xr + 32);
    f4 x3 = *(const f4*)(xr + 36);
    s8 X0, X1;
    X0[0]=(short)f2bf(x0.x); X0[1]=(short)f2bf(x0.y); X0[2]=(short)f2bf(x0.z); X0[3]=(short)f2bf(x0.w);
    X0[4]=(short)f2bf(x1.x); X0[5]=(short)f2bf(x1.y); X0[6]=(short)f2bf(x1.z); X0[7]=(short)f2bf(x1.w);
    X1[0]=(short)f2bf(x2.x); X1[1]=(short)f2bf(x2.y); X1[2]=(short)f2bf(x2.z); X1[3]=(short)f2bf(x2.w);
    X1[4]=(short)f2bf(x3.x); X1[5]=(short)f2bf(x3.y); X1[6]=(short)f2bf(x3.z); X1[7]=(short)f2bf(x3.w);

    f4 acc[8];
#pragma unroll
    for (int tt = 0; tt < 8; ++tt) acc[tt] = (f4)0.f;

#pragma unroll
    for (int s = 0; s < 2; ++s) {
        const s8 X = s ? X1 : X0;
#pragma unroll
        for (int tt = 0; tt < 8; ++tt) {
            // A-frag (W): A[m][k=s*32+q*8+j], 16B-aligned in padded LDS
            s8 w = *(const s8*)((const char*)Wl + (16 * tt + m) * 144 + s * 64 + q * 16);
            acc[tt] = __builtin_amdgcn_mfma_f32_16x16x32_bf16(w, X, acc[tt], 0, 0, 0);
        }
    }

    // D: o = 16*tt + q*4 + j, point = pbase + m  -> packed us4 (8B) stores
    const size_t prow = (size_t)(pbase + m) * 64;
#pragma unroll
    for (int tt = 0; tt < 4; ++tt) {
        us4 u;
        u.x = f2bf(acc[tt][0]); u.y = f2bf(acc[tt][1]);
        u.z = f2bf(acc[tt][2]); u.w = f2bf(acc[tt][3]);
        *(us4*)&Y1[prow + tt * 16 + q * 4] = u;
    }
#pragma unroll
    for (int tt = 4; tt < 8; ++tt) {
        us4 u;
        u.x = f2bf(acc[tt][0]); u.y = f2bf(acc[tt][1]);
        u.z = f2bf(acc[tt][2]); u.w = f2bf(acc[tt][3]);
        *(us4*)&Bs[prow + (tt - 4) * 16 + q * 4] = u;
    }
}

// ---------------- Kernel 2: gather + max + LN + GELU ----------------
// 8 points/wave, 8 lanes/point, 8 ch/lane: 16B gathers (half the VMEM instrs).
// XCD mapping (ROUND-3 CHANGE): sequential-batch-per-XCD. Old bt=bi&15 put
// batches x AND x+8 concurrently on XCD x -> 4.2MB of Y1 tables thrash the
// 4MB per-XCD L2. New: xcd=bi&7, bt = xcd + 8*(bi>>11) -> each XCD's resident
// cohort works ONE 2.1MB table at a time (fits L2 + stream headroom).
__global__ __launch_bounds__(256) void gather_kernel(const unsigned short* __restrict__ Y1,
                                                     const unsigned short* __restrict__ Bs,
                                                     const int* __restrict__ ind,
                                                     const float* __restrict__ gamma,
                                                     const float* __restrict__ beta,
                                                     float* __restrict__ out) {
    const int lane = threadIdx.x & 63;
    const int wave = threadIdx.x >> 6;
    const int sub = lane & 7;            // channel group (8 ch)
    const int q = lane >> 3;             // point within wave
    const int bi = blockIdx.x;           // 4096 blocks
    const int xcd = bi & 7;
    const int s2 = bi >> 3;              // 0..511
    const int bt = xcd + 8 * (s2 >> 8);  // batch: one table per XCD at a time
    const int jj = s2 & 255;             // 256 blocks per batch
    const int p = bt * N_ + jj * 32 + wave * 8 + q;
    const int bbase = bt * N_ * 64;

    int idxs[K_];
    const int4* ip = (const int4*)&ind[p * K_];   // 80B/point, 16B-aligned
#pragma unroll
    for (int v = 0; v < 5; ++v) {
        int4 iv = ip[v];
        idxs[4 * v + 0] = iv.x; idxs[4 * v + 1] = iv.y;
        idxs[4 * v + 2] = iv.z; idxs[4 * v + 3] = iv.w;
    }

    f4 ma = (f4)(-INFINITY), mb = (f4)(-INFINITY);
#pragma unroll
    for (int r = 0; r < 2; ++r) {        // 2 rounds x 10 outstanding 16B gathers
        u4 rv[10];
#pragma unroll
        for (int k = 0; k < 10; ++k)
            rv[k] = *(const u4*)(Y1 + bbase + idxs[r * 10 + k] * 64 + sub * 8);
#pragma unroll
        for (int k = 0; k < 10; ++k) {
            ma.x = fmaxf(ma.x, bflo(rv[k].x)); ma.y = fmaxf(ma.y, bfhi(rv[k].x));
            ma.z = fmaxf(ma.z, bflo(rv[k].y)); ma.w = fmaxf(ma.w, bfhi(rv[k].y));
            mb.x = fmaxf(mb.x, bflo(rv[k].z)); mb.y = fmaxf(mb.y, bfhi(rv[k].z));
            mb.z = fmaxf(mb.z, bflo(rv[k].w)); mb.w = fmaxf(mb.w, bfhi(rv[k].w));
        }
    }

    u4 bsv = __builtin_nontemporal_load((const u4*)(Bs + (size_t)p * 64 + sub * 8));
    f4 ha, hb;
    ha.x = ma.x + bflo(bsv.x); ha.y = ma.y + bfhi(bsv.x);
    ha.z = ma.z + bflo(bsv.y); ha.w = ma.w + bfhi(bsv.y);
    hb.x = mb.x + bflo(bsv.z); hb.y = mb.y + bfhi(bsv.z);
    hb.z = mb.z + bflo(bsv.w); hb.w = mb.w + bfhi(bsv.w);

    // LayerNorm over 64 ch = 8 comps x 8 lanes (xor masks 1,2,4 stay in-group)
    float s = ha.x + ha.y + ha.z + ha.w + hb.x + hb.y + hb.z + hb.w;
#pragma unroll
    for (int off = 4; off >= 1; off >>= 1) s += __shfl_xor(s, off, 64);
    const float mu = s * (1.0f / 64.0f);
    f4 da = ha - mu, db = hb - mu;
    float v2 = da.x * da.x + da.y * da.y + da.z * da.z + da.w * da.w
             + db.x * db.x + db.y * db.y + db.z * db.z + db.w * db.w;
#pragma unroll
    for (int off = 4; off >= 1; off >>= 1) v2 += __shfl_xor(v2, off, 64);
    const float rstd = rsqrtf(v2 * (1.0f / 64.0f) + 1e-5f);

    const f4 g0 = *(const f4*)&gamma[sub * 8];
    const f4 g1 = *(const f4*)&gamma[sub * 8 + 4];
    const f4 b0 = *(const f4*)&beta[sub * 8];
    const f4 b1 = *(const f4*)&beta[sub * 8 + 4];
    f4 na = da * rstd * g0 + b0;
    f4 nb = db * rstd * g1 + b1;

    f4 r0, r1;
    r0.x = 0.5f * na.x * (1.0f + erff(na.x * 0.70710678f));
    r0.y = 0.5f * na.y * (1.0f + erff(na.y * 0.70710678f));
    r0.z = 0.5f * na.z * (1.0f + erff(na.z * 0.70710678f));
    r0.w = 0.5f * na.w * (1.0f + erff(na.w * 0.70710678f));
    r1.x = 0.5f * nb.x * (1.0f + erff(nb.x * 0.70710678f));
    r1.y = 0.5f * nb.y * (1.0f + erff(nb.y * 0.70710678f));
    r1.z = 0.5f * nb.z * (1.0f + erff(nb.z * 0.70710678f));
    r1.w = 0.5f * nb.w * (1.0f + erff(nb.w * 0.70710678f));
    float* op = &out[(size_t)p * 64 + sub * 8];
    __builtin_nontemporal_store(r0, (f4*)op);
    __builtin_nontemporal_store(r1, (f4*)(op + 4));
}

extern "C" void kernel_launch(void* const* d_in, const int* in_sizes, int n_in,
                              void* d_out, int out_size, void* d_ws, size_t ws_size,
                              hipStream_t stream) {
    const float* x     = (const float*)d_in[0];
    const int*   ind   = (const int*)d_in[1];
    const float* W     = (const float*)d_in[2];
    const float* gamma = (const float*)d_in[3];
    const float* beta  = (const float*)d_in[4];
    float* out = (float*)d_out;

    unsigned short* Bs = (unsigned short*)d_ws;          // 16.8 MB bf16
    unsigned short* Y1 = Bs + (size_t)NPTS * 64;         // 16.8 MB bf16
    unsigned short* Wg = Y1 + (size_t)NPTS * 64;         // 16 KB bf16

    prep_kernel<<<32, 256, 0, stream>>>(W, Wg);
    proj_kernel<<<NPTS / 64, 256, 0, stream>>>(x, Wg, Y1, Bs);
    gather_kernel<<<NPTS / 32, 256, 0, stream>>>(Y1, Bs, ind, gamma, beta, out);
}